// Round 14
// baseline (161.229 us; speedup 1.0000x reference)
//
#include <hip/hip_runtime.h>

#define NBATCH 2
#define NHEAD  16
#define NSEQ   2048
#define NDIM   64
#define NNX    1024
#define NBH    (NBATCH*NHEAD)
#define CEXPF  0.18033688011112042f   // log2(e)/sqrt(64), folded into Qb at prep

typedef short          short8  __attribute__((ext_vector_type(8)));
typedef short          short4v __attribute__((ext_vector_type(4)));
typedef unsigned short us4     __attribute__((ext_vector_type(4)));
typedef unsigned short us8     __attribute__((ext_vector_type(8)));
typedef float          f32x4   __attribute__((ext_vector_type(4)));

__device__ __forceinline__ unsigned short f2bf(float f) {
    unsigned int u = __builtin_bit_cast(unsigned int, f);
    u += 0x7FFFu + ((u >> 16) & 1u);           // round-to-nearest-even
    return (unsigned short)(u >> 16);
}

__device__ __forceinline__ float fexp2(float x) {
#if __has_builtin(__builtin_amdgcn_exp2f)
    return __builtin_amdgcn_exp2f(x);
#else
    return exp2f(x);
#endif
}

__device__ __forceinline__ f32x4 mfma16(short8 a, short8 b, f32x4 c) {
    return __builtin_amdgcn_mfma_f32_16x16x32_bf16(a, b, c, 0, 0, 0);
}

// ---- prep: Qb = bf16 (query * CEXPF) split-heads [bh][s][d] (row layout);
// ----       KKb = bf16 (key+key_r) in MFMA-fragment order:
// ----       [bh][ktile][frag][lane][8], ktile stride 1024, frag stride 512.
__global__ __launch_bounds__(256) void prep_qk(
        const float* __restrict__ q, const float* __restrict__ k,
        const float* __restrict__ kr,
        unsigned short* __restrict__ Qb, unsigned short* __restrict__ KKb) {
    const long i    = (long)blockIdx.x * 256 + threadIdx.x;   // 0..1048575
    const long flat = i << 2;
    const int dnx = (int)(flat & (NNX - 1));
    const int s   = (int)((flat >> 10) & (NSEQ - 1));
    const int b   = (int)(flat >> 21);
    const int h   = dnx >> 6;
    const int d   = dnx & 63;                 // multiple of 4
    const int bh  = b*NHEAD + h;
    const long o  = ((long)bh * NSEQ + s) * NDIM + d;
    const int f   = d >> 5;
    const int g   = (d >> 3) & 3;
    const int j   = d & 7;                    // 0 or 4
    const long ko = (long)bh * (NSEQ*NDIM) + (s >> 4) * 1024 + f * 512
                  + (((g << 4) + (s & 15)) << 3) + j;
    const float4 qv = *(const float4*)(q  + flat);
    const float4 kv = *(const float4*)(k  + flat);
    const float4 rv = *(const float4*)(kr + flat);
    us4 qo, kko;
    qo[0]=f2bf(qv.x*CEXPF); qo[1]=f2bf(qv.y*CEXPF); qo[2]=f2bf(qv.z*CEXPF); qo[3]=f2bf(qv.w*CEXPF);
    kko[0]=f2bf(kv.x+rv.x); kko[1]=f2bf(kv.y+rv.y); kko[2]=f2bf(kv.z+rv.z); kko[3]=f2bf(kv.w+rv.w);
    *(us4*)(Qb  + o)  = qo;
    *(us4*)(KKb + ko) = kko;
}

// ---- prep: VF = bf16 value in PV-fragment order:
// ---- [bh][kt][dt][lane][4], lane = g*16 + r16,
// ---- element = V[d = dt*16 + r16][s = kt*16 + g*4 + j], j=0..3.
__global__ __launch_bounds__(256) void prep_vt(const float* __restrict__ v,
        unsigned short* __restrict__ VF) {
    __shared__ unsigned short lds[64][68];     // [head-dim][seq-local]
    const int bh = blockIdx.x & (NBH - 1);
    const int st = blockIdx.x >> 5;            // s-tile of 64
    const int b = bh >> 4, h = bh & 15;
    const int t  = threadIdx.x;
    const int sl = t >> 2;
    const int d0 = (t & 3) << 4;
    const float* src = v + ((long)b*NSEQ + st*64 + sl) * NNX + h*64 + d0;
    #pragma unroll
    for (int j = 0; j < 4; ++j) {
        float4 x = *(const float4*)(src + j*4);
        lds[d0 + j*4 + 0][sl] = f2bf(x.x);
        lds[d0 + j*4 + 1][sl] = f2bf(x.y);
        lds[d0 + j*4 + 2][sl] = f2bf(x.z);
        lds[d0 + j*4 + 3][sl] = f2bf(x.w);
    }
    __syncthreads();
    const int ktl = t >> 6;
    const int dt  = (t >> 4) & 3;
    const int b4  = (t & 15) << 2;
    us8 o0, o1;
    #pragma unroll
    for (int mg = 0; mg < 4; ++mg) {
        const int lp = b4 + mg;
        const int dd = dt*16 + (lp & 15);
        const int ss = ktl*16 + ((lp >> 4) << 2);
        #pragma unroll
        for (int j = 0; j < 4; ++j) {
            const unsigned short val = lds[dd][ss + j];
            if (mg < 2) o0[mg*4 + j] = val;
            else        o1[(mg-2)*4 + j] = val;
        }
    }
    unsigned short* dst = VF + (long)bh*(NDIM*NSEQ) + st*4096 + t*16;
    *(us8*)(dst)     = o0;
    *(us8*)(dst + 8) = o1;
}

// ---- fused attention: one 16-row q-tile per wave; 4-wave single-bh blocks.
// ---- bh = (bid&7)*4 + ((bid>>3)&3) keeps 4-bh-per-XCD affinity under bid%8.
// ---- att causal stores: 4 pairs batched in per-wave LDS, flushed as
// ---- 8 NT stores of 2 rows x 512B contiguous. ZERO-region stores are
// ---- interleaved into pass 1 (no data deps -> fills the idle store pipe).
__global__ __launch_bounds__(256, 4) void attn_main(
        const unsigned short* __restrict__ Qb,
        const unsigned short* __restrict__ KKb,
        const unsigned short* __restrict__ VF,
        float* __restrict__ outA, float* __restrict__ outAtt) {
    const int lane = threadIdx.x & 63;
    const int w    = threadIdx.x >> 6;                 // 0..3
    const int bh   = ((blockIdx.x & 7) << 2) | ((blockIdx.x >> 3) & 3);
    const int aIdx = ((blockIdx.x >> 5) << 1) | (w & 1);   // 0..63
    const int t    = (w < 2) ? aIdx : (127 - aIdx);    // q-tile 0..127
    const int b = bh >> 4, h = bh & 15;
    const int r16 = lane & 15;
    const int g   = lane >> 4;
    const int qbase = t << 4;
    const int qa  = qbase + r16;                       // this lane's q row

    // per-wave P batch buffer: 16 rows x 128 cols (4 pairs), row stride 132
    __shared__ float pbuf[4][16*132];                  // 33,792 B

    const unsigned short* Qp  = Qb  + (long)bh * (NSEQ*NDIM);
    const unsigned short* Kfp = KKb + (long)bh * (NSEQ*NDIM) + lane*8;
    const unsigned short* VFp = VF  + (long)bh * (NDIM*NSEQ) + lane*4;

    const short8 qf0 = *(const short8*)(Qp + qa*NDIM + g*8);
    const short8 qf1 = *(const short8*)(Qp + qa*NDIM + g*8 + 32);

    const f32x4 zero4 = {0.f,0.f,0.f,0.f};
    // flush/zero lane mapping: 2 rows x 512B spans
    float* gfl = outAtt + ((long)bh*NSEQ + qbase + (lane >> 5)) * NSEQ + ((lane & 31) << 2);

    // zero-region cursor: groups of 8 tiles, 8 instrs each (i = row-pair index)
    int zt = ((t & ~1) & ~7) + 8;                      // first zero group (> t always)
    int zi = 0;

    // ---------------- pass 1: row sums of exp2 + interleaved zero stores ----------------
    float ls[4] = {0.f,0.f,0.f,0.f};
    short8 c0 = *(const short8*)(Kfp);
    short8 c1 = *(const short8*)(Kfp + 512);
    for (int kt = 0; kt < t; ++kt) {               // tiles 0..t-1: never masked
        const short8 a0 = c0, a1 = c1;
        const unsigned short* np = Kfp + (kt + 1) * 1024;
        c0 = *(const short8*)(np);
        c1 = *(const short8*)(np + 512);
        f32x4 s = {0.f,0.f,0.f,0.f};
        s = mfma16(a0, qf0, s);
        s = mfma16(a1, qf1, s);
        #pragma unroll
        for (int r = 0; r < 4; ++r) ls[r] += fexp2(s[r]);
        if (zt < 128) {                            // one dependency-free zero store
            __builtin_nontemporal_store(zero4, (f32x4*)(gfl + (long)zi*2*NSEQ + (zt << 4)));
            if (++zi == 8) { zi = 0; zt += 8; }
        }
    }
    {   // diagonal tile t: mask col - row: g*4+r <= r16
        f32x4 s = {0.f,0.f,0.f,0.f};
        s = mfma16(c0, qf0, s);
        s = mfma16(c1, qf1, s);
        #pragma unroll
        for (int r = 0; r < 4; ++r) {
            const float e = fexp2(s[r]);
            ls[r] += (g*4 + r <= r16) ? e : 0.0f;
        }
    }
    // drain remaining zero stores (small-t waves)
    while (zt < 128) {
        __builtin_nontemporal_store(zero4, (f32x4*)(gfl + (long)zi*2*NSEQ + (zt << 4)));
        if (++zi == 8) { zi = 0; zt += 8; }
    }
    float l = ls[0]+ls[1]+ls[2]+ls[3];
    l += __shfl_xor(l, 16, 64);
    l += __shfl_xor(l, 32, 64);
    const float nl = log2f(l);                     // p = exp2(s - nl)

    // ---------------- pass 2: recompute, batch P in LDS, flush 512B spans, PV ----------------
    f32x4 oa[4];
    #pragma unroll
    for (int dt = 0; dt < 4; ++dt) oa[dt] = zero4;

    float* wp = &pbuf[w][r16*132 + (g << 2)];                          // P slot base
    const float* frp = &pbuf[w][(lane >> 5)*132 + ((lane & 31) << 2)]; // flush read base

#define FLUSH_BATCH(cbt) do {                                                     \
        const int cb_ = (cbt) << 4;                                               \
        _Pragma("unroll")                                                         \
        for (int i_ = 0; i_ < 8; ++i_) {                                          \
            const f32x4 vv_ = *(const f32x4*)(frp + i_*264);                      \
            __builtin_nontemporal_store(vv_, (f32x4*)(gfl + (long)i_*2*NSEQ + cb_)); \
        }                                                                         \
    } while (0)

    c0 = *(const short8*)(Kfp);
    c1 = *(const short8*)(Kfp + 512);
    const unsigned short* np1 = Kfp + ((t > 0) ? 1 : 0) * 1024;
    short8 d0 = *(const short8*)(np1);
    short8 d1 = *(const short8*)(np1 + 512);

    int kt = 0;
    for (; kt + 2 <= t; kt += 2) {                 // pairs of strictly-unmasked tiles
        const short8 a00 = c0, a01 = c1, a10 = d0, a11 = d1;
        const int i2 = (kt + 2 < t) ? kt + 2 : t;
        const int i3 = (kt + 3 < t) ? kt + 3 : t;
        const unsigned short* np2 = Kfp + i2 * 1024;
        const unsigned short* np3 = Kfp + i3 * 1024;
        c0 = *(const short8*)(np2); c1 = *(const short8*)(np2 + 512);
        d0 = *(const short8*)(np3); d1 = *(const short8*)(np3 + 512);

        short4v v0[4], v1[4];
        const unsigned short* vp0 = VFp + (kt << 2) * 256;
        #pragma unroll
        for (int dt = 0; dt < 4; ++dt) {
            v0[dt] = *(const short4v*)(vp0 + dt*256);
            v1[dt] = *(const short4v*)(vp0 + 1024 + dt*256);
        }

        f32x4 s0 = zero4, s1 = zero4;
        s0 = mfma16(a00, qf0, s0); s0 = mfma16(a01, qf1, s0);
        s1 = mfma16(a10, qf0, s1); s1 = mfma16(a11, qf1, s1);
        f32x4 p0, p1;
        #pragma unroll
        for (int r = 0; r < 4; ++r) {
            p0[r] = fexp2(s0[r] - nl);
            p1[r] = fexp2(s1[r] - nl);
        }
        const int pb = (kt >> 1) & 3;
        *(f32x4*)(wp + pb*32)      = p0;
        *(f32x4*)(wp + pb*32 + 16) = p1;

        short8 b0, b1;
        #pragma unroll
        for (int r = 0; r < 4; ++r) {
            b0[r] = (short)f2bf(p0[r]); b0[r+4] = 0;
            b1[r] = (short)f2bf(p1[r]); b1[r+4] = 0;
        }
        #pragma unroll
        for (int dt = 0; dt < 4; ++dt) {
            short8 av0, av1;
            av0[0]=v0[dt][0]; av0[1]=v0[dt][1]; av0[2]=v0[dt][2]; av0[3]=v0[dt][3];
            av0[4]=0; av0[5]=0; av0[6]=0; av0[7]=0;
            av1[0]=v1[dt][0]; av1[1]=v1[dt][1]; av1[2]=v1[dt][2]; av1[3]=v1[dt][3];
            av1[4]=0; av1[5]=0; av1[6]=0; av1[7]=0;
            oa[dt] = mfma16(av0, b0, oa[dt]);
            oa[dt] = mfma16(av1, b1, oa[dt]);
        }
        if (pb == 3) FLUSH_BATCH(kt & ~7);
    }
    {   // tail pair (kt = t&~1): even t -> (diag, zero); odd t -> (normal, diag)
        short4v v0[4], v1[4];
        const unsigned short* vp0 = VFp + (kt << 2) * 256;
        #pragma unroll
        for (int dt = 0; dt < 4; ++dt) {
            v0[dt] = *(const short4v*)(vp0 + dt*256);
            v1[dt] = *(const short4v*)(vp0 + 1024 + dt*256);   // tile kt+1 <= 127, in-bounds
        }
        f32x4 s0 = zero4;
        s0 = mfma16(c0, qf0, s0); s0 = mfma16(c1, qf1, s0);
        f32x4 p0, p1;
        if (kt == t) {          // even t: A = diagonal (masked), B = zeros
            #pragma unroll
            for (int r = 0; r < 4; ++r) {
                const float e = fexp2(s0[r] - nl);
                p0[r] = (g*4 + r <= r16) ? e : 0.0f;
                p1[r] = 0.0f;
            }
        } else {                // odd t: A = normal (tile t-1), B = diagonal (masked)
            f32x4 s1 = zero4;
            s1 = mfma16(d0, qf0, s1); s1 = mfma16(d1, qf1, s1);
            #pragma unroll
            for (int r = 0; r < 4; ++r) {
                p0[r] = fexp2(s0[r] - nl);
                const float e = fexp2(s1[r] - nl);
                p1[r] = (g*4 + r <= r16) ? e : 0.0f;
            }
        }
        const int pbt = (kt >> 1) & 3;
        *(f32x4*)(wp + pbt*32)      = p0;
        *(f32x4*)(wp + pbt*32 + 16) = p1;
        for (int pz = pbt + 1; pz < 4; ++pz) {     // zero-fill unused batch slots
            *(f32x4*)(wp + pz*32)      = zero4;
            *(f32x4*)(wp + pz*32 + 16) = zero4;
        }

        short8 b0, b1;
        #pragma unroll
        for (int r = 0; r < 4; ++r) {
            b0[r] = (short)f2bf(p0[r]); b0[r+4] = 0;
            b1[r] = (short)f2bf(p1[r]); b1[r+4] = 0;
        }
        #pragma unroll
        for (int dt = 0; dt < 4; ++dt) {
            short8 av0, av1;
            av0[0]=v0[dt][0]; av0[1]=v0[dt][1]; av0[2]=v0[dt][2]; av0[3]=v0[dt][3];
            av0[4]=0; av0[5]=0; av0[6]=0; av0[7]=0;
            av1[0]=v1[dt][0]; av1[1]=v1[dt][1]; av1[2]=v1[dt][2]; av1[3]=v1[dt][3];
            av1[4]=0; av1[5]=0; av1[6]=0; av1[7]=0;
            oa[dt] = mfma16(av0, b0, oa[dt]);
            oa[dt] = mfma16(av1, b1, oa[dt]);
        }
        FLUSH_BATCH(kt & ~7);
    }
    // (zero region already stored during/after pass 1)

    float* oA = outA + ((long)b*NSEQ + qa) * NNX + h*64 + (g << 2);
    #pragma unroll
    for (int dt = 0; dt < 4; ++dt)
        *(f32x4*)(oA + dt*16) = oa[dt];
#undef FLUSH_BATCH
}

extern "C" void kernel_launch(void* const* d_in, const int* in_sizes, int n_in,
                              void* d_out, int out_size, void* d_ws, size_t ws_size,
                              hipStream_t stream) {
    const float* q  = (const float*)d_in[0];
    const float* k  = (const float*)d_in[1];
    const float* v  = (const float*)d_in[2];
    const float* kr = (const float*)d_in[3];
    const size_t tensor_elems = (size_t)NBH * NSEQ * NDIM;   // 4,194,304
    if (ws_size < 3 * tensor_elems * sizeof(unsigned short)) return;  // need 24 MiB scratch
    unsigned short* Qb  = (unsigned short*)d_ws;
    unsigned short* KKb = Qb + tensor_elems;
    unsigned short* VF  = KKb + tensor_elems;
    float* outA   = (float*)d_out;
    float* outAtt = outA + (size_t)NBATCH * NSEQ * NNX;

    hipLaunchKernelGGL(prep_qk,   dim3(4096), dim3(256), 0, stream, q, k, kr, Qb, KKb);
    hipLaunchKernelGGL(prep_vt,   dim3(1024), dim3(256), 0, stream, v, VF);
    hipLaunchKernelGGL(attn_main, dim3(1024), dim3(256), 0, stream, Qb, KKb, VF, outA, outAtt);
}

// Round 15
// 142.877 us; speedup vs baseline: 1.1285x; 1.1285x over previous
//
#include <hip/hip_runtime.h>

#define NBATCH 2
#define NHEAD  16
#define NSEQ   2048
#define NDIM   64
#define NNX    1024
#define NBH    (NBATCH*NHEAD)
#define CEXPF  0.18033688011112042f   // log2(e)/sqrt(64), folded into Qb at prep

typedef short          short8  __attribute__((ext_vector_type(8)));
typedef short          short4v __attribute__((ext_vector_type(4)));
typedef unsigned short us4     __attribute__((ext_vector_type(4)));
typedef unsigned short us8     __attribute__((ext_vector_type(8)));
typedef float          f32x4   __attribute__((ext_vector_type(4)));

__device__ __forceinline__ unsigned short f2bf(float f) {
    unsigned int u = __builtin_bit_cast(unsigned int, f);
    u += 0x7FFFu + ((u >> 16) & 1u);           // round-to-nearest-even
    return (unsigned short)(u >> 16);
}

__device__ __forceinline__ float fexp2(float x) {
#if __has_builtin(__builtin_amdgcn_exp2f)
    return __builtin_amdgcn_exp2f(x);
#else
    return exp2f(x);
#endif
}

__device__ __forceinline__ f32x4 mfma16(short8 a, short8 b, f32x4 c) {
    return __builtin_amdgcn_mfma_f32_16x16x32_bf16(a, b, c, 0, 0, 0);
}

// ---- prep: Qb = bf16 (query * CEXPF) split-heads [bh][s][d] (row layout);
// ----       KKb = bf16 (key+key_r) in MFMA-fragment order:
// ----       [bh][ktile][frag][lane][8], ktile stride 1024, frag stride 512.
__global__ __launch_bounds__(256) void prep_qk(
        const float* __restrict__ q, const float* __restrict__ k,
        const float* __restrict__ kr,
        unsigned short* __restrict__ Qb, unsigned short* __restrict__ KKb) {
    const long i    = (long)blockIdx.x * 256 + threadIdx.x;   // 0..1048575
    const long flat = i << 2;
    const int dnx = (int)(flat & (NNX - 1));
    const int s   = (int)((flat >> 10) & (NSEQ - 1));
    const int b   = (int)(flat >> 21);
    const int h   = dnx >> 6;
    const int d   = dnx & 63;                 // multiple of 4
    const int bh  = b*NHEAD + h;
    const long o  = ((long)bh * NSEQ + s) * NDIM + d;
    const int f   = d >> 5;
    const int g   = (d >> 3) & 3;
    const int j   = d & 7;                    // 0 or 4
    const long ko = (long)bh * (NSEQ*NDIM) + (s >> 4) * 1024 + f * 512
                  + (((g << 4) + (s & 15)) << 3) + j;
    const float4 qv = *(const float4*)(q  + flat);
    const float4 kv = *(const float4*)(k  + flat);
    const float4 rv = *(const float4*)(kr + flat);
    us4 qo, kko;
    qo[0]=f2bf(qv.x*CEXPF); qo[1]=f2bf(qv.y*CEXPF); qo[2]=f2bf(qv.z*CEXPF); qo[3]=f2bf(qv.w*CEXPF);
    kko[0]=f2bf(kv.x+rv.x); kko[1]=f2bf(kv.y+rv.y); kko[2]=f2bf(kv.z+rv.z); kko[3]=f2bf(kv.w+rv.w);
    *(us4*)(Qb  + o)  = qo;
    *(us4*)(KKb + ko) = kko;
}

// ---- prep: VF = bf16 value in PV-fragment order:
// ---- [bh][kt][dt][lane][4], lane = g*16 + r16,
// ---- element = V[d = dt*16 + r16][s = kt*16 + g*4 + j], j=0..3.
__global__ __launch_bounds__(256) void prep_vt(const float* __restrict__ v,
        unsigned short* __restrict__ VF) {
    __shared__ unsigned short lds[64][68];     // [head-dim][seq-local]
    const int bh = blockIdx.x & (NBH - 1);
    const int st = blockIdx.x >> 5;            // s-tile of 64
    const int b = bh >> 4, h = bh & 15;
    const int t  = threadIdx.x;
    const int sl = t >> 2;
    const int d0 = (t & 3) << 4;
    const float* src = v + ((long)b*NSEQ + st*64 + sl) * NNX + h*64 + d0;
    #pragma unroll
    for (int j = 0; j < 4; ++j) {
        float4 x = *(const float4*)(src + j*4);
        lds[d0 + j*4 + 0][sl] = f2bf(x.x);
        lds[d0 + j*4 + 1][sl] = f2bf(x.y);
        lds[d0 + j*4 + 2][sl] = f2bf(x.z);
        lds[d0 + j*4 + 3][sl] = f2bf(x.w);
    }
    __syncthreads();
    const int ktl = t >> 6;
    const int dt  = (t >> 4) & 3;
    const int b4  = (t & 15) << 2;
    us8 o0, o1;
    #pragma unroll
    for (int mg = 0; mg < 4; ++mg) {
        const int lp = b4 + mg;
        const int dd = dt*16 + (lp & 15);
        const int ss = ktl*16 + ((lp >> 4) << 2);
        #pragma unroll
        for (int j = 0; j < 4; ++j) {
            const unsigned short val = lds[dd][ss + j];
            if (mg < 2) o0[mg*4 + j] = val;
            else        o1[(mg-2)*4 + j] = val;
        }
    }
    unsigned short* dst = VF + (long)bh*(NDIM*NSEQ) + st*4096 + t*16;
    *(us8*)(dst)     = o0;
    *(us8*)(dst + 8) = o1;
}

// ---- fused attention: one 16-row q-tile per wave; 4-wave single-bh blocks.
// ---- bh = (bid&7)*4 + ((bid>>3)&3) keeps 4-bh-per-XCD affinity under bid%8.
// ---- Per-block w->t rotation by (bid>>8)&3 so co-resident blocks place a MIX
// ---- of small-t and large-t waves on every SIMD (fixes per-SIMD compute
// ---- imbalance: R12 put all large-t waves on SIMDs 2/3).
// ---- att stores: 4 pairs batched in per-wave LDS, flushed as 8 NT stores
// ---- of 2 rows x 512B contiguous each.
__global__ __launch_bounds__(256, 4) void attn_main(
        const unsigned short* __restrict__ Qb,
        const unsigned short* __restrict__ KKb,
        const unsigned short* __restrict__ VF,
        float* __restrict__ outA, float* __restrict__ outAtt) {
    const int lane = threadIdx.x & 63;
    const int w    = threadIdx.x >> 6;                 // 0..3
    const int bh   = ((blockIdx.x & 7) << 2) | ((blockIdx.x >> 3) & 3);
    const int a0   = (blockIdx.x >> 5) << 1;           // block's aIdx base (0..62 even)
    const int rot  = (blockIdx.x >> 8) & 3;            // co-resident blocks rotate
    const int sel  = (w + rot) & 3;
    const int aX   = a0 | (sel >> 1);                  // a0 or a0+1
    const int t    = (sel & 1) ? (127 - aX) : aX;      // q-tile 0..127
    const int b = bh >> 4, h = bh & 15;
    const int r16 = lane & 15;
    const int g   = lane >> 4;
    const int qbase = t << 4;
    const int qa  = qbase + r16;                       // this lane's q row

    // per-wave P batch buffer: 16 rows x 128 cols (4 pairs), row stride 132
    __shared__ float pbuf[4][16*132];                  // 33,792 B

    const unsigned short* Qp  = Qb  + (long)bh * (NSEQ*NDIM);
    const unsigned short* Kfp = KKb + (long)bh * (NSEQ*NDIM) + lane*8;
    const unsigned short* VFp = VF  + (long)bh * (NDIM*NSEQ) + lane*4;

    const short8 qf0 = *(const short8*)(Qp + qa*NDIM + g*8);
    const short8 qf1 = *(const short8*)(Qp + qa*NDIM + g*8 + 32);

    // ---------------- pass 1: row sums of exp2 (S already in exp2 units) ----------------
    float ls[4] = {0.f,0.f,0.f,0.f};
    short8 c0 = *(const short8*)(Kfp);
    short8 c1 = *(const short8*)(Kfp + 512);
    #pragma unroll 2
    for (int kt = 0; kt < t; ++kt) {               // tiles 0..t-1: never masked
        const short8 a0v = c0, a1v = c1;
        const unsigned short* np = Kfp + (kt + 1) * 1024;
        c0 = *(const short8*)(np);
        c1 = *(const short8*)(np + 512);
        f32x4 s = {0.f,0.f,0.f,0.f};
        s = mfma16(a0v, qf0, s);
        s = mfma16(a1v, qf1, s);
        #pragma unroll
        for (int r = 0; r < 4; ++r) ls[r] += fexp2(s[r]);
    }
    {   // diagonal tile t: mask col - row: g*4+r <= r16
        f32x4 s = {0.f,0.f,0.f,0.f};
        s = mfma16(c0, qf0, s);
        s = mfma16(c1, qf1, s);
        #pragma unroll
        for (int r = 0; r < 4; ++r) {
            const float e = fexp2(s[r]);
            ls[r] += (g*4 + r <= r16) ? e : 0.0f;
        }
    }
    float l = ls[0]+ls[1]+ls[2]+ls[3];
    l += __shfl_xor(l, 16, 64);
    l += __shfl_xor(l, 32, 64);
    const float nl = log2f(l);                     // p = exp2(s - nl)

    // ---------------- pass 2: recompute, batch P in LDS, flush 512B spans, PV ----------------
    const f32x4 zero4 = {0.f,0.f,0.f,0.f};
    f32x4 oa[4];
    #pragma unroll
    for (int dt = 0; dt < 4; ++dt) oa[dt] = zero4;

    float* wp = &pbuf[w][r16*132 + (g << 2)];                          // P slot base
    const float* frp = &pbuf[w][(lane >> 5)*132 + ((lane & 31) << 2)]; // flush read base
    float* gfl = outAtt + ((long)bh*NSEQ + qbase + (lane >> 5)) * NSEQ + ((lane & 31) << 2);

#define FLUSH_BATCH(cbt) do {                                                     \
        const int cb_ = (cbt) << 4;                                               \
        _Pragma("unroll")                                                         \
        for (int i_ = 0; i_ < 8; ++i_) {                                          \
            const f32x4 vv_ = *(const f32x4*)(frp + i_*264);                      \
            __builtin_nontemporal_store(vv_, (f32x4*)(gfl + (long)i_*2*NSEQ + cb_)); \
        }                                                                         \
    } while (0)

    c0 = *(const short8*)(Kfp);
    c1 = *(const short8*)(Kfp + 512);
    const unsigned short* np1 = Kfp + ((t > 0) ? 1 : 0) * 1024;
    short8 d0 = *(const short8*)(np1);
    short8 d1 = *(const short8*)(np1 + 512);

    int kt = 0;
    for (; kt + 2 <= t; kt += 2) {                 // pairs of strictly-unmasked tiles
        const short8 a00 = c0, a01 = c1, a10 = d0, a11 = d1;
        const int i2 = (kt + 2 < t) ? kt + 2 : t;
        const int i3 = (kt + 3 < t) ? kt + 3 : t;
        const unsigned short* np2 = Kfp + i2 * 1024;
        const unsigned short* np3 = Kfp + i3 * 1024;
        c0 = *(const short8*)(np2); c1 = *(const short8*)(np2 + 512);
        d0 = *(const short8*)(np3); d1 = *(const short8*)(np3 + 512);

        short4v v0[4], v1[4];
        const unsigned short* vp0 = VFp + (kt << 2) * 256;
        #pragma unroll
        for (int dt = 0; dt < 4; ++dt) {
            v0[dt] = *(const short4v*)(vp0 + dt*256);
            v1[dt] = *(const short4v*)(vp0 + 1024 + dt*256);
        }

        f32x4 s0 = zero4, s1 = zero4;
        s0 = mfma16(a00, qf0, s0); s0 = mfma16(a01, qf1, s0);
        s1 = mfma16(a10, qf0, s1); s1 = mfma16(a11, qf1, s1);
        f32x4 p0, p1;
        #pragma unroll
        for (int r = 0; r < 4; ++r) {
            p0[r] = fexp2(s0[r] - nl);
            p1[r] = fexp2(s1[r] - nl);
        }
        const int pb = (kt >> 1) & 3;
        *(f32x4*)(wp + pb*32)      = p0;
        *(f32x4*)(wp + pb*32 + 16) = p1;

        short8 b0, b1;
        #pragma unroll
        for (int r = 0; r < 4; ++r) {
            b0[r] = (short)f2bf(p0[r]); b0[r+4] = 0;
            b1[r] = (short)f2bf(p1[r]); b1[r+4] = 0;
        }
        #pragma unroll
        for (int dt = 0; dt < 4; ++dt) {
            short8 av0, av1;
            av0[0]=v0[dt][0]; av0[1]=v0[dt][1]; av0[2]=v0[dt][2]; av0[3]=v0[dt][3];
            av0[4]=0; av0[5]=0; av0[6]=0; av0[7]=0;
            av1[0]=v1[dt][0]; av1[1]=v1[dt][1]; av1[2]=v1[dt][2]; av1[3]=v1[dt][3];
            av1[4]=0; av1[5]=0; av1[6]=0; av1[7]=0;
            oa[dt] = mfma16(av0, b0, oa[dt]);
            oa[dt] = mfma16(av1, b1, oa[dt]);
        }
        if (pb == 3) FLUSH_BATCH(kt & ~7);
    }
    {   // tail pair (kt = t&~1): even t -> (diag, zero); odd t -> (normal, diag)
        short4v v0[4], v1[4];
        const unsigned short* vp0 = VFp + (kt << 2) * 256;
        #pragma unroll
        for (int dt = 0; dt < 4; ++dt) {
            v0[dt] = *(const short4v*)(vp0 + dt*256);
            v1[dt] = *(const short4v*)(vp0 + 1024 + dt*256);   // tile kt+1 <= 127, in-bounds
        }
        f32x4 s0 = zero4;
        s0 = mfma16(c0, qf0, s0); s0 = mfma16(c1, qf1, s0);
        f32x4 p0, p1;
        if (kt == t) {          // even t: A = diagonal (masked), B = zeros
            #pragma unroll
            for (int r = 0; r < 4; ++r) {
                const float e = fexp2(s0[r] - nl);
                p0[r] = (g*4 + r <= r16) ? e : 0.0f;
                p1[r] = 0.0f;
            }
        } else {                // odd t: A = normal (tile t-1), B = diagonal (masked)
            f32x4 s1 = zero4;
            s1 = mfma16(d0, qf0, s1); s1 = mfma16(d1, qf1, s1);
            #pragma unroll
            for (int r = 0; r < 4; ++r) {
                p0[r] = fexp2(s0[r] - nl);
                const float e = fexp2(s1[r] - nl);
                p1[r] = (g*4 + r <= r16) ? e : 0.0f;
            }
        }
        const int pbt = (kt >> 1) & 3;
        *(f32x4*)(wp + pbt*32)      = p0;
        *(f32x4*)(wp + pbt*32 + 16) = p1;
        for (int pz = pbt + 1; pz < 4; ++pz) {     // zero-fill unused batch slots
            *(f32x4*)(wp + pz*32)      = zero4;
            *(f32x4*)(wp + pz*32 + 16) = zero4;
        }

        short8 b0, b1;
        #pragma unroll
        for (int r = 0; r < 4; ++r) {
            b0[r] = (short)f2bf(p0[r]); b0[r+4] = 0;
            b1[r] = (short)f2bf(p1[r]); b1[r+4] = 0;
        }
        #pragma unroll
        for (int dt = 0; dt < 4; ++dt) {
            short8 av0, av1;
            av0[0]=v0[dt][0]; av0[1]=v0[dt][1]; av0[2]=v0[dt][2]; av0[3]=v0[dt][3];
            av0[4]=0; av0[5]=0; av0[6]=0; av0[7]=0;
            av1[0]=v1[dt][0]; av1[1]=v1[dt][1]; av1[2]=v1[dt][2]; av1[3]=v1[dt][3];
            av1[4]=0; av1[5]=0; av1[6]=0; av1[7]=0;
            oa[dt] = mfma16(av0, b0, oa[dt]);
            oa[dt] = mfma16(av1, b1, oa[dt]);
        }
        FLUSH_BATCH(kt & ~7);
    }
    // zero the strictly-future batches: 2 rows x 512B NT stores
    for (int zt = ((t & ~1) & ~7) + 8; zt < 128; zt += 8) {
        const int cb = zt << 4;
        #pragma unroll
        for (int i = 0; i < 8; ++i)
            __builtin_nontemporal_store(zero4, (f32x4*)(gfl + (long)i*2*NSEQ + cb));
    }

    float* oA = outA + ((long)b*NSEQ + qa) * NNX + h*64 + (g << 2);
    #pragma unroll
    for (int dt = 0; dt < 4; ++dt)
        *(f32x4*)(oA + dt*16) = oa[dt];
#undef FLUSH_BATCH
}

extern "C" void kernel_launch(void* const* d_in, const int* in_sizes, int n_in,
                              void* d_out, int out_size, void* d_ws, size_t ws_size,
                              hipStream_t stream) {
    const float* q  = (const float*)d_in[0];
    const float* k  = (const float*)d_in[1];
    const float* v  = (const float*)d_in[2];
    const float* kr = (const float*)d_in[3];
    const size_t tensor_elems = (size_t)NBH * NSEQ * NDIM;   // 4,194,304
    if (ws_size < 3 * tensor_elems * sizeof(unsigned short)) return;  // need 24 MiB scratch
    unsigned short* Qb  = (unsigned short*)d_ws;
    unsigned short* KKb = Qb + tensor_elems;
    unsigned short* VF  = KKb + tensor_elems;
    float* outA   = (float*)d_out;
    float* outAtt = outA + (size_t)NBATCH * NSEQ * NNX;

    hipLaunchKernelGGL(prep_qk,   dim3(4096), dim3(256), 0, stream, q, k, kr, Qb, KKb);
    hipLaunchKernelGGL(prep_vt,   dim3(1024), dim3(256), 0, stream, v, VF);
    hipLaunchKernelGGL(attn_main, dim3(1024), dim3(256), 0, stream, Qb, KKb, VF, outA, outAtt);
}